// Round 1
// baseline (335.973 us; speedup 1.0000x reference)
//
#include <hip/hip_runtime.h>
#include <math.h>

// Gaussian blur, (64, 512, 512, 3) f32 NHWC, per-batch sigma.
// Reference's kernel k[b,di,dj] depends only on dj (xs broadcast bug in ref),
// so conv = vertical 3-row box sum, then horizontal [w0, w1, w0] over pixels
// (stride 3 floats in channel-interleaved layout).
//   s  = 3*stds[b];  e = exp(-1/s^2)
//   w1 = 1/(3*(1+2e));  w0 = e*w1

constexpr int Wd   = 512;
constexpr int Hd   = 512;
constexpr int Cd   = 3;
constexpr int ROWF = Wd * Cd;      // 1536 floats per row
constexpr int TPB  = ROWF / 4;     // 384 threads, one float4 each

__global__ __launch_bounds__(TPB) void gauss_row_kernel(
    const float* __restrict__ x,
    const float* __restrict__ stds,
    float* __restrict__ out)
{
    __shared__ float4 cs[TPB + 2];   // colsum for this row + zero halo

    const int t  = threadIdx.x;
    const int bi = blockIdx.x;       // = b*512 + i
    const int i  = bi & (Hd - 1);
    const int b  = bi >> 9;

    const float s  = stds[b] * 3.0f;
    const float e  = expf(-1.0f / (s * s));
    const float w1 = 1.0f / (3.0f * (1.0f + 2.0f * e));
    const float w0 = e * w1;

    const float* row = x + (size_t)bi * ROWF + (size_t)t * 4;

    // vertical box sum (block-uniform branches, zero padding at image top/bottom)
    float4 m = *(const float4*)(row);
    if (i > 0) {
        float4 a = *(const float4*)(row - ROWF);
        m.x += a.x; m.y += a.y; m.z += a.z; m.w += a.w;
    }
    if (i < Hd - 1) {
        float4 a = *(const float4*)(row + ROWF);
        m.x += a.x; m.y += a.y; m.z += a.z; m.w += a.w;
    }

    if (t == 0) {
        cs[0]       = make_float4(0.f, 0.f, 0.f, 0.f);
        cs[TPB + 1] = make_float4(0.f, 0.f, 0.f, 0.f);
    }
    cs[t + 1] = m;
    __syncthreads();

    const float4 p = cs[t];       // colsum[f-4 .. f-1]
    const float4 n = cs[t + 2];   // colsum[f+4 .. f+7]

    // out[f+k] = w1*colsum[f+k] + w0*(colsum[f+k-3] + colsum[f+k+3])
    float4 o;
    o.x = w1 * m.x + w0 * (p.y + m.w);
    o.y = w1 * m.y + w0 * (p.z + n.x);
    o.z = w1 * m.z + w0 * (p.w + n.y);
    o.w = w1 * m.w + w0 * (m.x + n.z);

    ((float4*)(out + (size_t)bi * ROWF))[t] = o;
}

extern "C" void kernel_launch(void* const* d_in, const int* in_sizes, int n_in,
                              void* d_out, int out_size, void* d_ws, size_t ws_size,
                              hipStream_t stream) {
    const float* x    = (const float*)d_in[0];
    const float* stds = (const float*)d_in[1];
    float* out        = (float*)d_out;

    const int nblocks = 64 * Hd;   // one block per (batch, row)
    gauss_row_kernel<<<nblocks, TPB, 0, stream>>>(x, stds, out);
}